// Round 4
// baseline (257.203 us; speedup 1.0000x reference)
//
#include <hip/hip_runtime.h>

#define N_FEAT 128
#define N_CLS 64

// 1) degree histogram over dst
__global__ __launch_bounds__(256) void k_deg(const int* __restrict__ dst, int ne,
                                             int* __restrict__ deg) {
    int i = blockIdx.x * blockDim.x + threadIdx.x;
    if (i < ne) atomicAdd(&deg[dst[i]], 1);
}

// 2a) per-block exclusive scan of deg (256 elems/block), emit block sums
__global__ __launch_bounds__(256) void k_scan1(const int* __restrict__ deg, int n,
                                               int* __restrict__ offtmp, int* __restrict__ bsum) {
    __shared__ int s[256];
    int t = threadIdx.x;
    int i = blockIdx.x * 256 + t;
    int v = (i < n) ? deg[i] : 0;
    s[t] = v;
    __syncthreads();
    for (int d = 1; d < 256; d <<= 1) {
        int u = (t >= d) ? s[t - d] : 0;
        __syncthreads();
        s[t] += u;
        __syncthreads();
    }
    if (i < n) offtmp[i] = s[t] - v;  // exclusive
    if (t == 255) bsum[blockIdx.x] = s[255];
}

// 2b) single tiny block: exclusive scan of block sums (nb <= 1024)
__global__ __launch_bounds__(1024) void k_scan2(int* __restrict__ bsum, int nb) {
    __shared__ int s[1024];
    int t = threadIdx.x;
    int v = (t < nb) ? bsum[t] : 0;
    s[t] = v;
    __syncthreads();
    for (int d = 1; d < 1024; d <<= 1) {
        int u = (t >= d) ? s[t - d] : 0;
        __syncthreads();
        s[t] += u;
        __syncthreads();
    }
    if (t < nb) bsum[t] = s[t] - v;  // exclusive
}

// 2c) finalize: off = offtmp + block offset; cur = off; nrm = rsqrt(max(deg,1))
__global__ __launch_bounds__(256) void k_scan3(const int* __restrict__ deg,
                                               const int* __restrict__ offtmp,
                                               const int* __restrict__ bsum, int n, int ne,
                                               int* __restrict__ off, int* __restrict__ cur,
                                               float* __restrict__ nrm) {
    int i = blockIdx.x * 256 + threadIdx.x;
    if (i < n) {
        int o = offtmp[i] + bsum[blockIdx.x];
        off[i] = o;
        cur[i] = o;
        nrm[i] = rsqrtf(fmaxf((float)deg[i], 1.0f));
    }
    if (i == 0) off[n] = ne;  // total edge count is known
}

// 3) counting-sort fill: esrc[off[dst]..off[dst]+deg) = src ids of edges into dst
__global__ __launch_bounds__(256) void k_fill(const int* __restrict__ src,
                                              const int* __restrict__ dst, int ne,
                                              int* __restrict__ cur, int* __restrict__ esrc) {
    int i = blockIdx.x * blockDim.x + threadIdx.x;
    if (i < ne) {
        int d = dst[i];
        int p = atomicAdd(&cur[d], 1);
        esrc[p] = src[i];
    }
}

// 4) Y[node] = (X[node] * nrm[node]) @ W
//    thread = (node, column-quarter): 4 threads/node, 16 fp32 accumulators each.
//    Lanes 0-3 share an X row (broadcast load); grid is 4x bigger -> ~12 waves/CU.
__global__ __launch_bounds__(256) void k_gemm(const float* __restrict__ X,
                                              const float* __restrict__ W,
                                              const float* __restrict__ nrm,
                                              float* __restrict__ Y, int n) {
    int tid = blockIdx.x * 256 + threadIdx.x;
    int node = tid >> 2;
    if (node >= n) return;
    int cq = (tid & 3) * 16;  // column base for this thread
    float acc[16];
#pragma unroll
    for (int c = 0; c < 16; ++c) acc[c] = 0.f;
    const float* xrow = X + (size_t)node * N_FEAT;
    for (int k4 = 0; k4 < N_FEAT; k4 += 4) {
        float4 xv = *(const float4*)(xrow + k4);
#pragma unroll
        for (int j = 0; j < 4; ++j) {
            float xj = (j == 0) ? xv.x : (j == 1) ? xv.y : (j == 2) ? xv.z : xv.w;
            const float* wrow = W + (size_t)(k4 + j) * N_CLS + cq;
#pragma unroll
            for (int c = 0; c < 16; c += 4) {
                float4 wv = *(const float4*)(wrow + c);
                acc[c + 0] = fmaf(xj, wv.x, acc[c + 0]);
                acc[c + 1] = fmaf(xj, wv.y, acc[c + 1]);
                acc[c + 2] = fmaf(xj, wv.z, acc[c + 2]);
                acc[c + 3] = fmaf(xj, wv.w, acc[c + 3]);
            }
        }
    }
    float nv = nrm[node];
    float* yrow = Y + (size_t)node * N_CLS + cq;
#pragma unroll
    for (int c = 0; c < 16; c += 4) {
        float4 o;
        o.x = acc[c + 0] * nv;
        o.y = acc[c + 1] * nv;
        o.z = acc[c + 2] * nv;
        o.w = acc[c + 3] * nv;
        *(float4*)(yrow + c) = o;
    }
}

// 5) wave-per-dst-node gather, 4 edge-slots x 16 lanes, float4/lane, unroll x2:
//    out[n][c] = nrm[n] * sum_{e into n} Y[esrc[e]][c] + b[c]
__global__ __launch_bounds__(256) void k_agg(const int* __restrict__ off,
                                             const int* __restrict__ esrc,
                                             const float* __restrict__ Y,
                                             const float* __restrict__ nrm,
                                             const float* __restrict__ b,
                                             float* __restrict__ out, int n) {
    int wid = (int)((blockIdx.x * (size_t)blockDim.x + threadIdx.x) >> 6);
    if (wid >= n) return;
    int lane = threadIdx.x & 63;
    int g = lane >> 4;        // edge slot 0..3
    int c = (lane & 15) * 4;  // column base (16 lanes x float4 = full 64-col row)
    int s = off[wid];
    int e = off[wid + 1];
    float4 a0 = make_float4(0.f, 0.f, 0.f, 0.f);
    float4 a1 = make_float4(0.f, 0.f, 0.f, 0.f);
    int p = s + g;
    for (; p + 4 < e; p += 8) {
        int s0 = esrc[p];
        int s1 = esrc[p + 4];
        float4 r0 = *(const float4*)(Y + (size_t)s0 * N_CLS + c);
        float4 r1 = *(const float4*)(Y + (size_t)s1 * N_CLS + c);
        a0.x += r0.x; a0.y += r0.y; a0.z += r0.z; a0.w += r0.w;
        a1.x += r1.x; a1.y += r1.y; a1.z += r1.z; a1.w += r1.w;
    }
    if (p < e) {
        int s0 = esrc[p];
        float4 r0 = *(const float4*)(Y + (size_t)s0 * N_CLS + c);
        a0.x += r0.x; a0.y += r0.y; a0.z += r0.z; a0.w += r0.w;
    }
    a0.x += a1.x; a0.y += a1.y; a0.z += a1.z; a0.w += a1.w;
    // reduce the 4 edge-slot partials: xor by 16 then 32
#pragma unroll
    for (int m = 16; m <= 32; m <<= 1) {
        a0.x += __shfl_xor(a0.x, m);
        a0.y += __shfl_xor(a0.y, m);
        a0.z += __shfl_xor(a0.z, m);
        a0.w += __shfl_xor(a0.w, m);
    }
    if (lane < 16) {
        float nv = nrm[wid];
        float4 bv = *(const float4*)(b + c);
        float4 o;
        o.x = a0.x * nv + bv.x;
        o.y = a0.y * nv + bv.y;
        o.z = a0.z * nv + bv.z;
        o.w = a0.w * nv + bv.w;
        *(float4*)(out + (size_t)wid * N_CLS + c) = o;
    }
}

extern "C" void kernel_launch(void* const* d_in, const int* in_sizes, int n_in,
                              void* d_out, int out_size, void* d_ws, size_t ws_size,
                              hipStream_t stream) {
    const float* X = (const float*)d_in[0];
    const float* W = (const float*)d_in[1];
    const float* b = (const float*)d_in[2];
    const int* src = (const int*)d_in[3];
    const int* dst = (const int*)d_in[4];
    int n = in_sizes[0] / N_FEAT;
    int ne = in_sizes[3];
    float* out = (float*)d_out;

    char* w = (char*)d_ws;
    auto take = [&](size_t bytes) {
        char* p = w;
        w += (bytes + 255) & ~(size_t)255;
        return p;
    };
    int nb = (n + 255) / 256;
    int* deg = (int*)take((size_t)n * 4);
    int* off = (int*)take((size_t)(n + 1) * 4);
    int* cur = (int*)take((size_t)n * 4);
    int* offtmp = (int*)take((size_t)n * 4);
    int* bsum = (int*)take((size_t)nb * 4);
    int* esrc = (int*)take((size_t)ne * 4);
    float* nrm = (float*)take((size_t)n * 4);
    float* Y = (float*)take((size_t)n * N_CLS * 4);

    hipMemsetAsync(deg, 0, (size_t)n * 4, stream);

    const int tb = 256;
    k_deg<<<(ne + tb - 1) / tb, tb, 0, stream>>>(dst, ne, deg);
    k_scan1<<<nb, 256, 0, stream>>>(deg, n, offtmp, bsum);
    k_scan2<<<1, 1024, 0, stream>>>(bsum, nb);
    k_scan3<<<nb, 256, 0, stream>>>(deg, offtmp, bsum, n, ne, off, cur, nrm);
    k_fill<<<(ne + tb - 1) / tb, tb, 0, stream>>>(src, dst, ne, cur, esrc);
    long long gemm_threads = (long long)n * 4;
    k_gemm<<<(int)((gemm_threads + tb - 1) / tb), tb, 0, stream>>>(X, W, nrm, Y, n);
    long long total_threads = (long long)n * 64;
    k_agg<<<(int)((total_threads + tb - 1) / tb), tb, 0, stream>>>(off, esrc, Y, nrm, b, out, n);
}

// Round 5
// 200.774 us; speedup vs baseline: 1.2811x; 1.2811x over previous
//
#include <hip/hip_runtime.h>

#define N_FEAT 128
#define N_CLS 64

// 1) degree histogram over dst
__global__ __launch_bounds__(256) void k_deg(const int* __restrict__ dst, int ne,
                                             int* __restrict__ deg) {
    int i = blockIdx.x * blockDim.x + threadIdx.x;
    if (i < ne) atomicAdd(&deg[dst[i]], 1);
}

// 2a) per-block exclusive scan of deg (256 elems/block), emit block sums
__global__ __launch_bounds__(256) void k_scan1(const int* __restrict__ deg, int n,
                                               int* __restrict__ offtmp, int* __restrict__ bsum) {
    __shared__ int s[256];
    int t = threadIdx.x;
    int i = blockIdx.x * 256 + t;
    int v = (i < n) ? deg[i] : 0;
    s[t] = v;
    __syncthreads();
    for (int d = 1; d < 256; d <<= 1) {
        int u = (t >= d) ? s[t - d] : 0;
        __syncthreads();
        s[t] += u;
        __syncthreads();
    }
    if (i < n) offtmp[i] = s[t] - v;  // exclusive
    if (t == 255) bsum[blockIdx.x] = s[255];
}

// 2b) single tiny block: exclusive scan of block sums (nb <= 1024)
__global__ __launch_bounds__(1024) void k_scan2(int* __restrict__ bsum, int nb) {
    __shared__ int s[1024];
    int t = threadIdx.x;
    int v = (t < nb) ? bsum[t] : 0;
    s[t] = v;
    __syncthreads();
    for (int d = 1; d < 1024; d <<= 1) {
        int u = (t >= d) ? s[t - d] : 0;
        __syncthreads();
        s[t] += u;
        __syncthreads();
    }
    if (t < nb) bsum[t] = s[t] - v;  // exclusive
}

// 2c) finalize: off = offtmp + block offset; cur = off; nrm = rsqrt(max(deg,1))
__global__ __launch_bounds__(256) void k_scan3(const int* __restrict__ deg,
                                               const int* __restrict__ offtmp,
                                               const int* __restrict__ bsum, int n, int ne,
                                               int* __restrict__ off, int* __restrict__ cur,
                                               float* __restrict__ nrm) {
    int i = blockIdx.x * 256 + threadIdx.x;
    if (i < n) {
        int o = offtmp[i] + bsum[blockIdx.x];
        off[i] = o;
        cur[i] = o;
        nrm[i] = rsqrtf(fmaxf((float)deg[i], 1.0f));
    }
    if (i == 0) off[n] = ne;  // total edge count is known
}

// 3) counting-sort fill: esrc[off[dst]..off[dst]+deg) = src ids of edges into dst
__global__ __launch_bounds__(256) void k_fill(const int* __restrict__ src,
                                              const int* __restrict__ dst, int ne,
                                              int* __restrict__ cur, int* __restrict__ esrc) {
    int i = blockIdx.x * blockDim.x + threadIdx.x;
    if (i < ne) {
        int d = dst[i];
        int p = atomicAdd(&cur[d], 1);
        esrc[p] = src[i];
    }
}

// 4) Y[node] = (X[node] * nrm[node]) @ W
//    Block = 64 nodes (lanes) x 4 waves; wave = (khalf, chalf), BOTH wave-uniform
//    (readfirstlane) so W addresses are SGPR-derived -> s_load broadcast.
//    Each thread: acc[32] over K=64. khalf=1 partials go through LDS, 1 barrier.
__global__ __launch_bounds__(256) void k_gemm(const float* __restrict__ X,
                                              const float* __restrict__ W,
                                              const float* __restrict__ nrm,
                                              float* __restrict__ Y, int n) {
    __shared__ float red[64][65];  // pad 65: bank = (lane + c) % 32, conflict-free
    int t = threadIdx.x;
    int wv = __builtin_amdgcn_readfirstlane(t >> 6);  // wave id 0..3, SGPR
    int khalf = wv >> 1;
    int chalf = wv & 1;
    int lane = t & 63;
    int node = blockIdx.x * 64 + lane;
    bool valid = node < n;
    int cbase = chalf * 32;
    int kbase = khalf * 64;

    float acc[32];
#pragma unroll
    for (int c = 0; c < 32; ++c) acc[c] = 0.f;

    const float* xrow = X + (size_t)node * N_FEAT + kbase;
    const float* wbase = W + (size_t)kbase * N_CLS + cbase;
#pragma unroll
    for (int k4 = 0; k4 < 64; k4 += 4) {
        float4 xv = make_float4(0.f, 0.f, 0.f, 0.f);
        if (valid) xv = *(const float4*)(xrow + k4);
#pragma unroll
        for (int j = 0; j < 4; ++j) {
            float xj = (j == 0) ? xv.x : (j == 1) ? xv.y : (j == 2) ? xv.z : xv.w;
            const float* wrow = wbase + (size_t)(k4 + j) * N_CLS;  // uniform addr
#pragma unroll
            for (int c = 0; c < 32; c += 4) {
                float4 wv4 = *(const float4*)(wrow + c);
                acc[c + 0] = fmaf(xj, wv4.x, acc[c + 0]);
                acc[c + 1] = fmaf(xj, wv4.y, acc[c + 1]);
                acc[c + 2] = fmaf(xj, wv4.z, acc[c + 2]);
                acc[c + 3] = fmaf(xj, wv4.w, acc[c + 3]);
            }
        }
    }

    if (khalf == 1) {
#pragma unroll
        for (int c = 0; c < 32; ++c) red[lane][cbase + c] = acc[c];
    }
    __syncthreads();
    if (khalf == 0 && valid) {
        float nv = nrm[node];
#pragma unroll
        for (int c = 0; c < 32; ++c) acc[c] += red[lane][cbase + c];
        float* yrow = Y + (size_t)node * N_CLS + cbase;
#pragma unroll
        for (int c = 0; c < 32; c += 4) {
            float4 o;
            o.x = acc[c + 0] * nv;
            o.y = acc[c + 1] * nv;
            o.z = acc[c + 2] * nv;
            o.w = acc[c + 3] * nv;
            *(float4*)(yrow + c) = o;
        }
    }
}

// 5) wave-per-dst-node gather, 4 edge-slots x 16 lanes, float4/lane, unroll x2:
//    out[n][c] = nrm[n] * sum_{e into n} Y[esrc[e]][c] + b[c]
__global__ __launch_bounds__(256) void k_agg(const int* __restrict__ off,
                                             const int* __restrict__ esrc,
                                             const float* __restrict__ Y,
                                             const float* __restrict__ nrm,
                                             const float* __restrict__ b,
                                             float* __restrict__ out, int n) {
    int wid = (int)((blockIdx.x * (size_t)blockDim.x + threadIdx.x) >> 6);
    if (wid >= n) return;
    int lane = threadIdx.x & 63;
    int g = lane >> 4;        // edge slot 0..3
    int c = (lane & 15) * 4;  // column base (16 lanes x float4 = full 64-col row)
    int s = off[wid];
    int e = off[wid + 1];
    float4 a0 = make_float4(0.f, 0.f, 0.f, 0.f);
    float4 a1 = make_float4(0.f, 0.f, 0.f, 0.f);
    int p = s + g;
    for (; p + 4 < e; p += 8) {
        int s0 = esrc[p];
        int s1 = esrc[p + 4];
        float4 r0 = *(const float4*)(Y + (size_t)s0 * N_CLS + c);
        float4 r1 = *(const float4*)(Y + (size_t)s1 * N_CLS + c);
        a0.x += r0.x; a0.y += r0.y; a0.z += r0.z; a0.w += r0.w;
        a1.x += r1.x; a1.y += r1.y; a1.z += r1.z; a1.w += r1.w;
    }
    if (p < e) {
        int s0 = esrc[p];
        float4 r0 = *(const float4*)(Y + (size_t)s0 * N_CLS + c);
        a0.x += r0.x; a0.y += r0.y; a0.z += r0.z; a0.w += r0.w;
    }
    a0.x += a1.x; a0.y += a1.y; a0.z += a1.z; a0.w += a1.w;
    // reduce the 4 edge-slot partials: xor by 16 then 32
#pragma unroll
    for (int m = 16; m <= 32; m <<= 1) {
        a0.x += __shfl_xor(a0.x, m);
        a0.y += __shfl_xor(a0.y, m);
        a0.z += __shfl_xor(a0.z, m);
        a0.w += __shfl_xor(a0.w, m);
    }
    if (lane < 16) {
        float nv = nrm[wid];
        float4 bv = *(const float4*)(b + c);
        float4 o;
        o.x = a0.x * nv + bv.x;
        o.y = a0.y * nv + bv.y;
        o.z = a0.z * nv + bv.z;
        o.w = a0.w * nv + bv.w;
        *(float4*)(out + (size_t)wid * N_CLS + c) = o;
    }
}

extern "C" void kernel_launch(void* const* d_in, const int* in_sizes, int n_in,
                              void* d_out, int out_size, void* d_ws, size_t ws_size,
                              hipStream_t stream) {
    const float* X = (const float*)d_in[0];
    const float* W = (const float*)d_in[1];
    const float* b = (const float*)d_in[2];
    const int* src = (const int*)d_in[3];
    const int* dst = (const int*)d_in[4];
    int n = in_sizes[0] / N_FEAT;
    int ne = in_sizes[3];
    float* out = (float*)d_out;

    char* w = (char*)d_ws;
    auto take = [&](size_t bytes) {
        char* p = w;
        w += (bytes + 255) & ~(size_t)255;
        return p;
    };
    int nb = (n + 255) / 256;
    int* deg = (int*)take((size_t)n * 4);
    int* off = (int*)take((size_t)(n + 1) * 4);
    int* cur = (int*)take((size_t)n * 4);
    int* offtmp = (int*)take((size_t)n * 4);
    int* bsum = (int*)take((size_t)nb * 4);
    int* esrc = (int*)take((size_t)ne * 4);
    float* nrm = (float*)take((size_t)n * 4);
    float* Y = (float*)take((size_t)n * N_CLS * 4);

    hipMemsetAsync(deg, 0, (size_t)n * 4, stream);

    const int tb = 256;
    k_deg<<<(ne + tb - 1) / tb, tb, 0, stream>>>(dst, ne, deg);
    k_scan1<<<nb, 256, 0, stream>>>(deg, n, offtmp, bsum);
    k_scan2<<<1, 1024, 0, stream>>>(bsum, nb);
    k_scan3<<<nb, 256, 0, stream>>>(deg, offtmp, bsum, n, ne, off, cur, nrm);
    k_fill<<<(ne + tb - 1) / tb, tb, 0, stream>>>(src, dst, ne, cur, esrc);
    int gemm_blocks = (n + 63) / 64;
    k_gemm<<<gemm_blocks, 256, 0, stream>>>(X, W, nrm, Y, n);
    long long total_threads = (long long)n * 64;
    k_agg<<<(int)((total_threads + tb - 1) / tb), tb, 0, stream>>>(off, esrc, Y, nrm, b, out, n);
}

// Round 6
// 172.716 us; speedup vs baseline: 1.4892x; 1.1625x over previous
//
#include <hip/hip_runtime.h>

#define N_FEAT 128
#define N_CLS 64

// 1) degree histogram over dst (int4-vectorized)
__global__ __launch_bounds__(256) void k_deg(const int* __restrict__ dst, int ne,
                                             int* __restrict__ deg) {
    int i = (blockIdx.x * blockDim.x + threadIdx.x) * 4;
    if (i + 3 < ne) {
        int4 d = *(const int4*)(dst + i);
        atomicAdd(&deg[d.x], 1);
        atomicAdd(&deg[d.y], 1);
        atomicAdd(&deg[d.z], 1);
        atomicAdd(&deg[d.w], 1);
    } else {
        for (; i < ne; ++i) atomicAdd(&deg[dst[i]], 1);
    }
}

// 2a) per-block exclusive scan of deg (256 elems/block), emit block sums
__global__ __launch_bounds__(256) void k_scan1(const int* __restrict__ deg, int n,
                                               int* __restrict__ offtmp, int* __restrict__ bsum) {
    __shared__ int s[256];
    int t = threadIdx.x;
    int i = blockIdx.x * 256 + t;
    int v = (i < n) ? deg[i] : 0;
    s[t] = v;
    __syncthreads();
    for (int d = 1; d < 256; d <<= 1) {
        int u = (t >= d) ? s[t - d] : 0;
        __syncthreads();
        s[t] += u;
        __syncthreads();
    }
    if (i < n) offtmp[i] = s[t] - v;  // exclusive
    if (t == 255) bsum[blockIdx.x] = s[255];
}

// 2b) single tiny block: exclusive scan of block sums (nb <= 1024)
__global__ __launch_bounds__(1024) void k_scan2(int* __restrict__ bsum, int nb) {
    __shared__ int s[1024];
    int t = threadIdx.x;
    int v = (t < nb) ? bsum[t] : 0;
    s[t] = v;
    __syncthreads();
    for (int d = 1; d < 1024; d <<= 1) {
        int u = (t >= d) ? s[t - d] : 0;
        __syncthreads();
        s[t] += u;
        __syncthreads();
    }
    if (t < nb) bsum[t] = s[t] - v;  // exclusive
}

// 2c) finalize: off = offtmp + block offset; cur = off; nrm = rsqrt(max(deg,1))
__global__ __launch_bounds__(256) void k_scan3(const int* __restrict__ deg,
                                               const int* __restrict__ offtmp,
                                               const int* __restrict__ bsum, int n, int ne,
                                               int* __restrict__ off, int* __restrict__ cur,
                                               float* __restrict__ nrm) {
    int i = blockIdx.x * 256 + threadIdx.x;
    if (i < n) {
        int o = offtmp[i] + bsum[blockIdx.x];
        off[i] = o;
        cur[i] = o;
        nrm[i] = rsqrtf(fmaxf((float)deg[i], 1.0f));
    }
    if (i == 0) off[n] = ne;  // total edge count is known
}

// 3) counting-sort fill (int4-vectorized loads)
__global__ __launch_bounds__(256) void k_fill(const int* __restrict__ src,
                                              const int* __restrict__ dst, int ne,
                                              int* __restrict__ cur, int* __restrict__ esrc) {
    int i = (blockIdx.x * blockDim.x + threadIdx.x) * 4;
    if (i + 3 < ne) {
        int4 d = *(const int4*)(dst + i);
        int4 s = *(const int4*)(src + i);
        esrc[atomicAdd(&cur[d.x], 1)] = s.x;
        esrc[atomicAdd(&cur[d.y], 1)] = s.y;
        esrc[atomicAdd(&cur[d.z], 1)] = s.z;
        esrc[atomicAdd(&cur[d.w], 1)] = s.w;
    } else {
        for (; i < ne; ++i) esrc[atomicAdd(&cur[dst[i]], 1)] = src[i];
    }
}

// 4) Y[node] = (X[node] * nrm[node]) @ W
//    W (128x64 = 32 KB) resident in LDS for the whole kernel (one barrier).
//    Block = 128 threads; thread (s=tid>>2, q=tid&3) computes 4 nodes
//    {base+s+32i} x 16 cols [16q,16q+16). acc[4][16]; W ds_read_b128 reused
//    across the 4 nodes -> VALU-bound 2.6:1; no barriers in the k-loop.
__global__ __launch_bounds__(128) void k_gemm(const float* __restrict__ X,
                                              const float* __restrict__ W,
                                              const float* __restrict__ nrm,
                                              float* __restrict__ Y, int n) {
    __shared__ float wl[N_FEAT * N_CLS];  // 32 KB
    int t = threadIdx.x;
    // stage W: 8192 floats / 128 threads = 16 float4 each, coalesced
    const float4* W4 = (const float4*)W;
    float4* wl4 = (float4*)wl;
#pragma unroll
    for (int i = 0; i < 16; ++i) wl4[t + i * 128] = W4[t + i * 128];
    __syncthreads();

    int s = t >> 2;
    int q = t & 3;
    int cq = q * 16;
    int base = blockIdx.x * 128;

    int node[4];
    bool valid[4];
    const float* xr[4];
#pragma unroll
    for (int i = 0; i < 4; ++i) {
        node[i] = base + s + 32 * i;
        valid[i] = node[i] < n;
        xr[i] = X + (size_t)node[i] * N_FEAT;
    }

    float acc[4][16];
#pragma unroll
    for (int i = 0; i < 4; ++i)
#pragma unroll
        for (int c = 0; c < 16; ++c) acc[i][c] = 0.f;

    for (int k4 = 0; k4 < N_FEAT; k4 += 4) {
        float4 xv[4];
#pragma unroll
        for (int i = 0; i < 4; ++i)
            xv[i] = valid[i] ? *(const float4*)(xr[i] + k4) : make_float4(0.f, 0.f, 0.f, 0.f);
#pragma unroll
        for (int j = 0; j < 4; ++j) {
            const float4* wr = (const float4*)(wl + (k4 + j) * N_CLS + cq);
            float4 w0 = wr[0], w1 = wr[1], w2 = wr[2], w3 = wr[3];
#pragma unroll
            for (int i = 0; i < 4; ++i) {
                float xj = (j == 0) ? xv[i].x : (j == 1) ? xv[i].y : (j == 2) ? xv[i].z : xv[i].w;
                acc[i][0] = fmaf(xj, w0.x, acc[i][0]);
                acc[i][1] = fmaf(xj, w0.y, acc[i][1]);
                acc[i][2] = fmaf(xj, w0.z, acc[i][2]);
                acc[i][3] = fmaf(xj, w0.w, acc[i][3]);
                acc[i][4] = fmaf(xj, w1.x, acc[i][4]);
                acc[i][5] = fmaf(xj, w1.y, acc[i][5]);
                acc[i][6] = fmaf(xj, w1.z, acc[i][6]);
                acc[i][7] = fmaf(xj, w1.w, acc[i][7]);
                acc[i][8] = fmaf(xj, w2.x, acc[i][8]);
                acc[i][9] = fmaf(xj, w2.y, acc[i][9]);
                acc[i][10] = fmaf(xj, w2.z, acc[i][10]);
                acc[i][11] = fmaf(xj, w2.w, acc[i][11]);
                acc[i][12] = fmaf(xj, w3.x, acc[i][12]);
                acc[i][13] = fmaf(xj, w3.y, acc[i][13]);
                acc[i][14] = fmaf(xj, w3.z, acc[i][14]);
                acc[i][15] = fmaf(xj, w3.w, acc[i][15]);
            }
        }
    }

#pragma unroll
    for (int i = 0; i < 4; ++i) {
        if (!valid[i]) continue;
        float nv = nrm[node[i]];
        float* yrow = Y + (size_t)node[i] * N_CLS + cq;
#pragma unroll
        for (int c = 0; c < 16; c += 4) {
            float4 o;
            o.x = acc[i][c + 0] * nv;
            o.y = acc[i][c + 1] * nv;
            o.z = acc[i][c + 2] * nv;
            o.w = acc[i][c + 3] * nv;
            *(float4*)(yrow + c) = o;
        }
    }
}

// 5) wave-per-dst-node gather, 4 edge-slots x 16 lanes, float4/lane, unroll x2:
//    out[n][c] = nrm[n] * sum_{e into n} Y[esrc[e]][c] + b[c]
__global__ __launch_bounds__(256) void k_agg(const int* __restrict__ off,
                                             const int* __restrict__ esrc,
                                             const float* __restrict__ Y,
                                             const float* __restrict__ nrm,
                                             const float* __restrict__ b,
                                             float* __restrict__ out, int n) {
    int wid = (int)((blockIdx.x * (size_t)blockDim.x + threadIdx.x) >> 6);
    if (wid >= n) return;
    int lane = threadIdx.x & 63;
    int g = lane >> 4;        // edge slot 0..3
    int c = (lane & 15) * 4;  // column base (16 lanes x float4 = full 64-col row)
    int s = off[wid];
    int e = off[wid + 1];
    float4 a0 = make_float4(0.f, 0.f, 0.f, 0.f);
    float4 a1 = make_float4(0.f, 0.f, 0.f, 0.f);
    int p = s + g;
    for (; p + 4 < e; p += 8) {
        int s0 = esrc[p];
        int s1 = esrc[p + 4];
        float4 r0 = *(const float4*)(Y + (size_t)s0 * N_CLS + c);
        float4 r1 = *(const float4*)(Y + (size_t)s1 * N_CLS + c);
        a0.x += r0.x; a0.y += r0.y; a0.z += r0.z; a0.w += r0.w;
        a1.x += r1.x; a1.y += r1.y; a1.z += r1.z; a1.w += r1.w;
    }
    if (p < e) {
        int s0 = esrc[p];
        float4 r0 = *(const float4*)(Y + (size_t)s0 * N_CLS + c);
        a0.x += r0.x; a0.y += r0.y; a0.z += r0.z; a0.w += r0.w;
    }
    a0.x += a1.x; a0.y += a1.y; a0.z += a1.z; a0.w += a1.w;
#pragma unroll
    for (int m = 16; m <= 32; m <<= 1) {
        a0.x += __shfl_xor(a0.x, m);
        a0.y += __shfl_xor(a0.y, m);
        a0.z += __shfl_xor(a0.z, m);
        a0.w += __shfl_xor(a0.w, m);
    }
    if (lane < 16) {
        float nv = nrm[wid];
        float4 bv = *(const float4*)(b + c);
        float4 o;
        o.x = a0.x * nv + bv.x;
        o.y = a0.y * nv + bv.y;
        o.z = a0.z * nv + bv.z;
        o.w = a0.w * nv + bv.w;
        *(float4*)(out + (size_t)wid * N_CLS + c) = o;
    }
}

extern "C" void kernel_launch(void* const* d_in, const int* in_sizes, int n_in,
                              void* d_out, int out_size, void* d_ws, size_t ws_size,
                              hipStream_t stream) {
    const float* X = (const float*)d_in[0];
    const float* W = (const float*)d_in[1];
    const float* b = (const float*)d_in[2];
    const int* src = (const int*)d_in[3];
    const int* dst = (const int*)d_in[4];
    int n = in_sizes[0] / N_FEAT;
    int ne = in_sizes[3];
    float* out = (float*)d_out;

    char* w = (char*)d_ws;
    auto take = [&](size_t bytes) {
        char* p = w;
        w += (bytes + 255) & ~(size_t)255;
        return p;
    };
    int nb = (n + 255) / 256;
    int* deg = (int*)take((size_t)n * 4);
    int* off = (int*)take((size_t)(n + 1) * 4);
    int* cur = (int*)take((size_t)n * 4);
    int* offtmp = (int*)take((size_t)n * 4);
    int* bsum = (int*)take((size_t)nb * 4);
    int* esrc = (int*)take((size_t)ne * 4);
    float* nrm = (float*)take((size_t)n * 4);
    float* Y = (float*)take((size_t)n * N_CLS * 4);

    hipMemsetAsync(deg, 0, (size_t)n * 4, stream);

    const int tb = 256;
    int ne4 = (ne + 3) / 4;
    k_deg<<<(ne4 + tb - 1) / tb, tb, 0, stream>>>(dst, ne, deg);
    k_scan1<<<nb, 256, 0, stream>>>(deg, n, offtmp, bsum);
    k_scan2<<<1, 1024, 0, stream>>>(bsum, nb);
    k_scan3<<<nb, 256, 0, stream>>>(deg, offtmp, bsum, n, ne, off, cur, nrm);
    k_fill<<<(ne4 + tb - 1) / tb, tb, 0, stream>>>(src, dst, ne, cur, esrc);
    int gemm_blocks = (n + 127) / 128;
    k_gemm<<<gemm_blocks, 128, 0, stream>>>(X, W, nrm, Y, n);
    long long total_threads = (long long)n * 64;
    k_agg<<<(int)((total_threads + tb - 1) / tb), tb, 0, stream>>>(off, esrc, Y, nrm, b, out, n);
}